// Round 15
// baseline (147.541 us; speedup 1.0000x reference)
//
#include <hip/hip_runtime.h>

// N=50000, E=800000 (per relation), D=128, O=128, fp32 in/out.
// out = relu( spmm(adj1, X@W1) + spmm(adj2, X@W2) )
//      = relu( spmm(adj1, X) @ W1 + spmm(adj2, X) @ W2 )   [associativity]
//
// Pipeline (all on `stream`, graph-capture safe):
//   convbin: [blocks 0..511] bin edges -> 196 coarse 256-row buckets,
//            LDS write-combined (196 keys x 40 slots = 63KB; mean fill 16
//            -> ~128B flush runs). Pack {val:f32 | col:16 | rel:1 | rowLocal:8}.
//            [blocks 512..767] convert: Xb = bf16(X), Wt = bf16(W^T).
//   sort:    per coarse bucket (196 blocks): LDS counting-sort ~8.2K edges
//            by seg = rowLocal | rel<<8 (REL-MAJOR, 512 segs); in-place
//            write-back + seg_ptr[513].
//   agg:     block = (bucket, 16-row quarter) (grid 3136). NO LDS, no
//            rescan: 32-lane groups walk seg ranges [e0,e1) of the sorted
//            list (broadcast 8B packs), gather ushort4 slices of Xb[col],
//            fp32 accum, bf16 agg store. seg = rel*256 + q*16 + rowLocalQ
//            (MUST match sort's rel-major order -- r14's bug was interleaved
//            indexing here).
//   gemm:    out = relu( agg0 @ W1 + agg1 @ W2 ) via 16x16x32 bf16 MFMA.
//
// Ledger (measured): r7 split agg=54.7 gemm~12 convert~8 bin~52 tot=129.6;
// r13 agg+gemm fusion regressed (91us, occ 35.8%). r11: XCD pinning not
// durable. r9: work-stealing kills locality.

typedef __attribute__((ext_vector_type(4))) float     f32x4;
typedef __attribute__((ext_vector_type(8))) short     bf16x8;

#define NBC     196     // coarse 256-row buckets: ceil(50000/256)
#define BSLOTS  40      // LDS staging slots per bucket in bin (mean fill 16)
#define BCAPC   9216    // capacity per coarse bucket (mean 8192, ~11 sigma)
#define BING    512     // bin blocks
#define CONVG   256     // convert blocks
#define SPITCH  516     // seg_ptr pitch (513 used)

static __device__ __forceinline__ unsigned short f2bf(float f) {
    unsigned u = __float_as_uint(f);
    u += 0x7FFF + ((u >> 16) & 1);           // round-to-nearest-even
    return (unsigned short)(u >> 16);
}
static __device__ __forceinline__ float b2f(unsigned short s) {
    return __uint_as_float((unsigned)s << 16);
}

// ---------------------------------------------------------------------------
// Fused: bin (blocks < BING) + convert (blocks >= BING).
// pack lo32 = rowLocal(8) | rel<<8 | col<<9 ; hi32 = val bits.
// ---------------------------------------------------------------------------
__global__ __launch_bounds__(256) void convbin_kernel(
    const float* __restrict__ X,
    const float* __restrict__ W1, const float* __restrict__ W2,
    const int* __restrict__ rows1, const int* __restrict__ cols1, const float* __restrict__ vals1,
    const int* __restrict__ rows2, const int* __restrict__ cols2, const float* __restrict__ vals2,
    unsigned short* __restrict__ Xb, unsigned short* __restrict__ Wt,
    int* __restrict__ gcur, unsigned long long* __restrict__ edges_tmp,
    int E, int n)
{
    if (blockIdx.x >= BING) {
        // ---- convert role ----
        const int stride = CONVG * 256;
        const int nW = 2 * 128 * 128;
        const int nX = n * 32;               // float4 count
        const int total = nW + nX;
        for (int g = (blockIdx.x - BING) * 256 + threadIdx.x; g < total; g += stride) {
            if (g < nW) {
                const int rel = g >> 14;
                const int o   = (g >> 7) & 127;
                const int k   = g & 127;
                const float* W = rel ? W2 : W1;
                Wt[g] = f2bf(W[k * 128 + o]);
            } else {
                const int i = g - nW;
                const float4 v = ((const float4*)X)[i];
                ushort4 b;
                b.x = f2bf(v.x); b.y = f2bf(v.y); b.z = f2bf(v.z); b.w = f2bf(v.w);
                ((ushort4*)Xb)[i] = b;
            }
        }
        return;
    }

    // ---- bin role: coarse 256-row buckets ----
    __shared__ unsigned long long stage[NBC][BSLOTS];    // 62.7 KB
    __shared__ int scnt[NBC];

    for (int i = threadIdx.x; i < NBC; i += 256) scnt[i] = 0;
    __syncthreads();

    const int stride = BING * 256;
    const int total  = 2 * E;
    for (int g = blockIdx.x * 256 + threadIdx.x; g < total; g += stride) {
        int r, col, rel; float v;
        if (g < E) { r = rows1[g]; col = cols1[g]; rel = 0; v = vals1[g]; }
        else       { int e = g - E; r = rows2[e]; col = cols2[e]; rel = 1; v = vals2[e]; }

        const int b = r >> 8;
        const unsigned lo = (unsigned)(r & 255) | ((unsigned)rel << 8) | ((unsigned)col << 9);
        const unsigned long long pack =
            (unsigned long long)lo | ((unsigned long long)__float_as_uint(v) << 32);

        const int pos = atomicAdd(&scnt[b], 1);
        if (pos < BSLOTS) {
            stage[b][pos] = pack;
        } else {                                  // overflow: direct write
            int gp = atomicAdd(&gcur[b], 1);
            if (gp < BCAPC) edges_tmp[(size_t)b * BCAPC + gp] = pack;
        }
    }
    __syncthreads();

    for (int b = threadIdx.x; b < NBC; b += 256) {
        int k = scnt[b]; if (k > BSLOTS) k = BSLOTS;
        if (k > 0) {
            int base = atomicAdd(&gcur[b], k);
            for (int i = 0; i < k; ++i)
                if (base + i < BCAPC)
                    edges_tmp[(size_t)b * BCAPC + base + i] = stage[b][i];
        }
    }
}

// ---------------------------------------------------------------------------
// Sort: per coarse bucket, counting-sort edges IN PLACE by
// seg = lo & 511 = rowLocal | rel<<8 (REL-MAJOR); emit seg_ptr[513].
// ---------------------------------------------------------------------------
__global__ __launch_bounds__(256) void sort_kernel(
    const int* __restrict__ gcur,
    unsigned long long* __restrict__ edges_tmp,
    int* __restrict__ seg_ptr)
{
    __shared__ unsigned long long sout[BCAPC];           // 73.7 KB
    __shared__ int hist[512];
    __shared__ int ptr[513];
    __shared__ int cur[512];
    __shared__ int wsum[4];

    const int b   = blockIdx.x;
    const int tid = threadIdx.x;
    int sz = gcur[b]; if (sz > BCAPC) sz = BCAPC;
    unsigned long long* ebase = edges_tmp + (size_t)b * BCAPC;

    hist[tid] = 0; hist[tid + 256] = 0;
    __syncthreads();

    // Phase A: histogram (seg = lo & 511)
    for (int e = tid; e < sz; e += 256) {
        const unsigned lo = (unsigned)ebase[e];
        atomicAdd(&hist[lo & 511u], 1);
    }
    __syncthreads();

    // Phase B: exclusive scan of 512 via 256-thread pair scan
    {
        const int h0 = hist[2 * tid], h1 = hist[2 * tid + 1];
        const int p  = h0 + h1;
        const int lane = tid & 63, wid = tid >> 6;
        int x = p;
        #pragma unroll
        for (int off = 1; off < 64; off <<= 1) {
            int t = __shfl_up(x, off, 64);
            if (lane >= off) x += t;
        }
        if (lane == 63) wsum[wid] = x;
        __syncthreads();
        int wbase = 0;
        #pragma unroll
        for (int wI = 0; wI < 4; ++wI) if (wI < wid) wbase += wsum[wI];
        const int ex = wbase + x - p;            // exclusive pair prefix
        ptr[2 * tid]     = ex;
        ptr[2 * tid + 1] = ex + h0;
        if (tid == 255) ptr[512] = ex + p;
        cur[2 * tid]     = ex;
        cur[2 * tid + 1] = ex + h0;
    }
    __syncthreads();

    // Phase C: scatter into LDS at sorted positions
    for (int e = tid; e < sz; e += 256) {
        const unsigned long long p = ebase[e];
        const int pos = atomicAdd(&cur[(unsigned)p & 511u], 1);
        sout[pos] = p;
    }
    __syncthreads();

    // Phase D: coalesced in-place write-back + seg_ptr
    for (int e = tid; e < sz; e += 256) ebase[e] = sout[e];
    for (int i = tid; i <= 512; i += 256) seg_ptr[b * SPITCH + i] = ptr[i];
}

// ---------------------------------------------------------------------------
// Agg: block = (coarse bucket, 16-row quarter). No LDS. 8 groups x 32
// lanes; group handles 4 (row,rel) pairs. seg = rel*256 + q*16 + rowLocalQ
// (rel-major -- matches sort). Per edge: broadcast 8B pack + ushort4 gather
// per lane; fp32 accum; bf16 store.
// ---------------------------------------------------------------------------
__global__ __launch_bounds__(256) void agg_kernel(
    const unsigned long long* __restrict__ edges_tmp,
    const int* __restrict__ seg_ptr,
    const unsigned short* __restrict__ Xb,
    unsigned short* __restrict__ agg, int n)
{
    const int tid  = threadIdx.x;
    const int lane = tid & 31;
    const int grp  = tid >> 5;

    const int NQ = NBC * 16;                 // 3136 = 8 * 392
    const int xcd = blockIdx.x & 7, bi = blockIdx.x >> 3;
    const int swz = xcd * (NQ >> 3) + bi;    // m204 swizzle (r8 == 0)

    const int cb = swz >> 4;
    const int q  = swz & 15;
    const int rowbase = cb * 256 + q * 16;
    if (rowbase >= n) return;

    const unsigned long long* ebase = edges_tmp + (size_t)cb * BCAPC;
    const int* sptr = seg_ptr + cb * SPITCH;

    for (int si = grp; si < 32; si += 8) {
        const int rlq = si >> 1;             // rowLocal within quarter
        const int rel = si & 1;
        const int row = rowbase + rlq;
        if (row >= n) continue;
        const int seg = rel * 256 + q * 16 + rlq;   // rel-major (sort order)
        const int e0 = sptr[seg], e1 = sptr[seg + 1];

        float4 acc = make_float4(0.f, 0.f, 0.f, 0.f);
        int e = e0;
        for (; e + 4 <= e1; e += 4) {
            const unsigned long long p0 = ebase[e + 0];
            const unsigned long long p1 = ebase[e + 1];
            const unsigned long long p2 = ebase[e + 2];
            const unsigned long long p3 = ebase[e + 3];
            const ushort4 x0 = *(const ushort4*)&Xb[(size_t)(((unsigned)p0 >> 9) & 0xFFFFu) * 128 + lane * 4];
            const ushort4 x1 = *(const ushort4*)&Xb[(size_t)(((unsigned)p1 >> 9) & 0xFFFFu) * 128 + lane * 4];
            const ushort4 x2 = *(const ushort4*)&Xb[(size_t)(((unsigned)p2 >> 9) & 0xFFFFu) * 128 + lane * 4];
            const ushort4 x3 = *(const ushort4*)&Xb[(size_t)(((unsigned)p3 >> 9) & 0xFFFFu) * 128 + lane * 4];
            const float v0 = __uint_as_float((unsigned)(p0 >> 32));
            const float v1 = __uint_as_float((unsigned)(p1 >> 32));
            const float v2 = __uint_as_float((unsigned)(p2 >> 32));
            const float v3 = __uint_as_float((unsigned)(p3 >> 32));
            acc.x = fmaf(v0, b2f(x0.x), acc.x);
            acc.y = fmaf(v0, b2f(x0.y), acc.y);
            acc.z = fmaf(v0, b2f(x0.z), acc.z);
            acc.w = fmaf(v0, b2f(x0.w), acc.w);
            acc.x = fmaf(v1, b2f(x1.x), acc.x);
            acc.y = fmaf(v1, b2f(x1.y), acc.y);
            acc.z = fmaf(v1, b2f(x1.z), acc.z);
            acc.w = fmaf(v1, b2f(x1.w), acc.w);
            acc.x = fmaf(v2, b2f(x2.x), acc.x);
            acc.y = fmaf(v2, b2f(x2.y), acc.y);
            acc.z = fmaf(v2, b2f(x2.z), acc.z);
            acc.w = fmaf(v2, b2f(x2.w), acc.w);
            acc.x = fmaf(v3, b2f(x3.x), acc.x);
            acc.y = fmaf(v3, b2f(x3.y), acc.y);
            acc.z = fmaf(v3, b2f(x3.z), acc.z);
            acc.w = fmaf(v3, b2f(x3.w), acc.w);
        }
        for (; e < e1; ++e) {
            const unsigned long long p = ebase[e];
            const ushort4 xv = *(const ushort4*)&Xb[(size_t)(((unsigned)p >> 9) & 0xFFFFu) * 128 + lane * 4];
            const float v  = __uint_as_float((unsigned)(p >> 32));
            acc.x = fmaf(v, b2f(xv.x), acc.x);
            acc.y = fmaf(v, b2f(xv.y), acc.y);
            acc.z = fmaf(v, b2f(xv.z), acc.z);
            acc.w = fmaf(v, b2f(xv.w), acc.w);
        }

        ushort4 o;
        o.x = f2bf(acc.x); o.y = f2bf(acc.y); o.z = f2bf(acc.z); o.w = f2bf(acc.w);
        *(ushort4*)&agg[((size_t)rel * n + row) * 128 + lane * 4] = o;
    }
}

// ---------------------------------------------------------------------------
// GEMM epilogue (r7-proven): out = relu( agg0 @ W1 + agg1 @ W2 ).
// 32-row tiles. A-frag: row = lane&15, k = (lane>>4)*8 + j. C/D: col=lane&15,
// row=(lane>>4)*4+reg  [m89-verified].
// ---------------------------------------------------------------------------
__global__ __launch_bounds__(256) void gemm_relu_kernel(
    const unsigned short* __restrict__ agg,
    const unsigned short* __restrict__ Wt,
    float* __restrict__ out, int n)
{
    const int lane = threadIdx.x & 63;
    const int w    = threadIdx.x >> 6;
    const int colbase = w * 32;
    const int l15 = lane & 15;
    const int lhi = lane >> 4;

    bf16x8 bfrag[2][2][4];                   // [rel][ct][ks]
    #pragma unroll
    for (int rel = 0; rel < 2; ++rel) {
        const unsigned short* Wr = Wt + rel * 16384;
        #pragma unroll
        for (int ct = 0; ct < 2; ++ct) {
            const int o = colbase + ct * 16 + l15;
            #pragma unroll
            for (int ks = 0; ks < 4; ++ks)
                bfrag[rel][ct][ks] = *(const bf16x8*)&Wr[o * 128 + ks * 32 + lhi * 8];
        }
    }

    const int row0 = blockIdx.x * 32;
    const f32x4 zero = {0.f, 0.f, 0.f, 0.f};

    #pragma unroll
    for (int rt = 0; rt < 2; ++rt) {
        const int r0 = row0 + rt * 16;
        int ra = r0 + l15; if (ra >= n) ra = n - 1;   // clamp OOB reads
        bf16x8 af0[4], af1[4];
        #pragma unroll
        for (int ks = 0; ks < 4; ++ks) {
            af0[ks] = *(const bf16x8*)&agg[(size_t)ra * 128 + ks * 32 + lhi * 8];
            af1[ks] = *(const bf16x8*)&agg[((size_t)n + ra) * 128 + ks * 32 + lhi * 8];
        }

        f32x4 acc[2];
        acc[0] = zero; acc[1] = zero;
        #pragma unroll
        for (int ks = 0; ks < 4; ++ks) {
            acc[0] = __builtin_amdgcn_mfma_f32_16x16x32_bf16(af0[ks], bfrag[0][0][ks], acc[0], 0, 0, 0);
            acc[1] = __builtin_amdgcn_mfma_f32_16x16x32_bf16(af0[ks], bfrag[0][1][ks], acc[1], 0, 0, 0);
            acc[0] = __builtin_amdgcn_mfma_f32_16x16x32_bf16(af1[ks], bfrag[1][0][ks], acc[0], 0, 0, 0);
            acc[1] = __builtin_amdgcn_mfma_f32_16x16x32_bf16(af1[ks], bfrag[1][1][ks], acc[1], 0, 0, 0);
        }

        #pragma unroll
        for (int ct = 0; ct < 2; ++ct) {
            const int col = colbase + ct * 16 + l15;
            #pragma unroll
            for (int j = 0; j < 4; ++j) {
                const int r = r0 + lhi * 4 + j;
                if (r < n) out[(size_t)r * 128 + col] = fmaxf(acc[ct][j], 0.f);
            }
        }
    }
}

extern "C" void kernel_launch(void* const* d_in, const int* in_sizes, int n_in,
                              void* d_out, int out_size, void* d_ws, size_t ws_size,
                              hipStream_t stream)
{
    const float* X  = (const float*)d_in[0];
    const int*   r1 = (const int*)  d_in[1];
    const int*   c1 = (const int*)  d_in[2];
    const float* v1 = (const float*)d_in[3];
    const int*   r2 = (const int*)  d_in[4];
    const int*   c2 = (const int*)  d_in[5];
    const float* v2 = (const float*)d_in[6];
    const float* W1 = (const float*)d_in[7];
    const float* W2 = (const float*)d_in[8];
    float*       out = (float*)d_out;

    const int n = in_sizes[0] / 128;   // 50000
    const int E = in_sizes[1];         // 800000

    // Workspace layout (~54 MB):
    //   agg       : 2*n*128 bf16    (25.6 MB)
    //   Xb        : n*128 bf16      (12.8 MB)
    //   Wt        : 2*128*128 bf16  (64 KB)
    //   edges_tmp : NBC*BCAPC u64   (14.5 MB), 256B-aligned
    //   seg_ptr   : NBC*SPITCH ints (404 KB)
    //   gcur      : NBC ints
    unsigned short* agg = (unsigned short*)d_ws;
    unsigned short* Xb  = agg + (size_t)2 * n * 128;
    unsigned short* Wt  = Xb + (size_t)n * 128;
    unsigned long long* edges_tmp =
        (unsigned long long*)(((uintptr_t)(Wt + 2 * 128 * 128) + 255) & ~(uintptr_t)255);
    int* seg_ptr = (int*)(edges_tmp + (size_t)NBC * BCAPC);
    int* gcur    = seg_ptr + NBC * SPITCH;

    hipMemsetAsync(gcur, 0, NBC * sizeof(int), stream);

    // 1) bin (coarse) + convert (fused, disjoint block ranges)
    convbin_kernel<<<BING + CONVG, 256, 0, stream>>>(
        X, W1, W2, r1, c1, v1, r2, c2, v2, Xb, Wt, gcur, edges_tmp, E, n);

    // 2) counting-sort each coarse bucket by (rel, rowLocal)
    sort_kernel<<<NBC, 256, 0, stream>>>(gcur, edges_tmp, seg_ptr);

    // 3) aggregate straight from sorted segments (no LDS, no rescan)
    agg_kernel<<<NBC * 16, 256, 0, stream>>>(edges_tmp, seg_ptr, Xb, agg, n);

    // 4) GEMM + ReLU epilogue
    gemm_relu_kernel<<<(n + 31) / 32, 256, 0, stream>>>(agg, Wt, out, n);
}